// Round 1
// baseline (533.104 us; speedup 1.0000x reference)
//
#include <hip/hip_runtime.h>

// Problem constants
constexpr int Bn  = 8;
constexpr int Cn  = 1024;
constexpr int Tn  = 4096;
constexpr int Hn  = 16;
constexpr int Kn  = 15;
constexpr int PADn = 7;   // K/2

// ---------------------------------------------------------------------------
// Kernel A: proj[b,t,f] = sum_c x[b,c,t] * W[f,c]; softmax over k within head;
// write w laid out as (B, H, K, T) into workspace (30 MiB).
// grid (Tn/16, Bn), block 256. Thread = (h = tid>>4, kk = tid&15); kk==15 idle
// for compute but participates in staging.
// LDS: xs[512 rows][20 floats] (16 t's + 4 pad), two c-phases of 512 rows.
// ---------------------------------------------------------------------------
__global__ __launch_bounds__(256)
void lwc_weights(const float* __restrict__ x,
                 const float* __restrict__ W,
                 float* __restrict__ wout)
{
    __shared__ __align__(16) float xs[512 * 20];

    const int tid = threadIdx.x;
    const int t0  = blockIdx.x * 16;
    const int b   = blockIdx.y;
    const int h   = tid >> 4;
    const int kk  = tid & 15;
    const bool valid = (kk < 15);
    const int f   = h * 15 + (valid ? kk : 14);

    float acc[16];
#pragma unroll
    for (int i = 0; i < 16; ++i) acc[i] = 0.f;

    const float4* Wrow = reinterpret_cast<const float4*>(W + (size_t)f * Cn);

    for (int p = 0; p < 2; ++p) {
        const int cbase = p * 512;
        // ---- stage x[b, cbase:cbase+512, t0:t0+16] into LDS ----
#pragma unroll
        for (int i = 0; i < 8; ++i) {
            const int idx = tid + 256 * i;          // 0..2047
            const int cl  = idx >> 2;               // 0..511
            const int tt4 = (idx & 3) * 4;          // 0,4,8,12
            const float4 v = *reinterpret_cast<const float4*>(
                x + ((size_t)b * Cn + cbase + cl) * Tn + t0 + tt4);
            *reinterpret_cast<float4*>(xs + cl * 20 + tt4) = v;
        }
        __syncthreads();

        // ---- accumulate: acc[tt] += W[f][c] * xs[c][tt] ----
        const float4* Wp = Wrow + (cbase >> 2);
        for (int i = 0; i < 128; ++i) {
            const float4 w4 = Wp[i];
            float wc[4] = {w4.x, w4.y, w4.z, w4.w};
#pragma unroll
            for (int r = 0; r < 4; ++r) {
                const float4* xp = reinterpret_cast<const float4*>(xs + (i * 4 + r) * 20);
                const float4 a0 = xp[0], a1 = xp[1], a2 = xp[2], a3 = xp[3];
                const float xv[16] = {a0.x, a0.y, a0.z, a0.w,
                                      a1.x, a1.y, a1.z, a1.w,
                                      a2.x, a2.y, a2.z, a2.w,
                                      a3.x, a3.y, a3.z, a3.w};
#pragma unroll
                for (int tt = 0; tt < 16; ++tt) acc[tt] += wc[r] * xv[tt];
            }
        }
        __syncthreads();
    }

    // ---- softmax over the 15 taps (16-lane groups, lane kk==15 excluded) ----
    float wbuf[16];
#pragma unroll
    for (int tt = 0; tt < 16; ++tt) {
        float v = valid ? acc[tt] : -3.0e38f;
        float m = v;
#pragma unroll
        for (int off = 8; off >= 1; off >>= 1)
            m = fmaxf(m, __shfl_xor(m, off, 16));
        float e = valid ? expf(v - m) : 0.f;
        float s = e;
#pragma unroll
        for (int off = 8; off >= 1; off >>= 1)
            s += __shfl_xor(s, off, 16);
        wbuf[tt] = e / s;
    }

    if (valid) {
        float* wrow = wout + (((size_t)b * Hn + h) * Kn + kk) * Tn + t0;
#pragma unroll
        for (int q = 0; q < 4; ++q) {
            float4 o;
            o.x = wbuf[4 * q + 0]; o.y = wbuf[4 * q + 1];
            o.z = wbuf[4 * q + 2]; o.w = wbuf[4 * q + 3];
            *reinterpret_cast<float4*>(wrow + 4 * q) = o;
        }
    }
}

// ---------------------------------------------------------------------------
// Kernel B: out[b,c,t] = sum_k w[b, c%H, k, t] * x[b, c, t+k-7]
// grid (Tn/1024, Hn*4, Bn), block 256. Each block: one head h, one quarter of
// its 64 channels (16 channels), one 1024-wide t chunk. w taps live in
// registers (15 x float4 per thread, coalesced loads), x row staged in LDS.
// ---------------------------------------------------------------------------
__global__ __launch_bounds__(256)
void lwc_apply(const float* __restrict__ x,
               const float* __restrict__ w,
               float* __restrict__ out)
{
    __shared__ __align__(16) float xsh[1040];   // covers [t0-8, t0+1032)

    const int tid = threadIdx.x;
    const int t0  = blockIdx.x * 1024;
    const int h   = blockIdx.y >> 2;
    const int rq  = blockIdx.y & 3;      // which 16-channel quarter
    const int b   = blockIdx.z;
    const int tb  = 4 * tid;             // thread's base t within chunk

    // load this (b,h,t-chunk)'s 15 taps: wreg[k] covers t0+tb .. t0+tb+3
    float4 wreg[15];
#pragma unroll
    for (int k = 0; k < 15; ++k)
        wreg[k] = *reinterpret_cast<const float4*>(
            w + (((size_t)b * Hn + h) * Kn + k) * Tn + t0 + tb);

    for (int rr = 0; rr < 16; ++rr) {
        const int r = rq * 16 + rr;
        const int c = r * Hn + h;
        const float* xrow = x + ((size_t)b * Cn + c) * Tn;

        // stage x[c, t0-8 : t0+1032) with zero padding at sequence edges
        for (int i = tid; i < 1040; i += 256) {
            const int g = t0 - 8 + i;
            xsh[i] = ((unsigned)g < (unsigned)Tn) ? xrow[g] : 0.f;
        }
        __syncthreads();

        float xv[20];
        const float4* xp = reinterpret_cast<const float4*>(xsh + tb);
#pragma unroll
        for (int q = 0; q < 5; ++q) {
            const float4 a = xp[q];
            xv[4 * q + 0] = a.x; xv[4 * q + 1] = a.y;
            xv[4 * q + 2] = a.z; xv[4 * q + 3] = a.w;
        }

        // out(t = t0+tb+j) = sum_k wreg[k][j] * x[t+k-7] = xv[j+k+1]
        float ox = 0.f, oy = 0.f, oz = 0.f, ow = 0.f;
#pragma unroll
        for (int k = 0; k < 15; ++k) {
            ox += wreg[k].x * xv[k + 1];
            oy += wreg[k].y * xv[k + 2];
            oz += wreg[k].z * xv[k + 3];
            ow += wreg[k].w * xv[k + 4];
        }
        float4 o; o.x = ox; o.y = oy; o.z = oz; o.w = ow;
        *reinterpret_cast<float4*>(out + ((size_t)b * Cn + c) * Tn + t0 + tb) = o;
        __syncthreads();   // protect xsh before next channel's restage
    }
}

// ---------------------------------------------------------------------------
// kernel_launch
// d_in[0] = x (B,C,T) f32; d_in[1] = W_lin (H*K, C) f32; d_out = (B,C,T) f32.
// d_ws: needs B*H*K*T*4 = 30 MiB for the softmaxed kernels (layout B,H,K,T).
// ---------------------------------------------------------------------------
extern "C" void kernel_launch(void* const* d_in, const int* in_sizes, int n_in,
                              void* d_out, int out_size, void* d_ws, size_t ws_size,
                              hipStream_t stream)
{
    const float* x = (const float*)d_in[0];
    const float* W = (const float*)d_in[1];
    float* out     = (float*)d_out;
    float* wks     = (float*)d_ws;   // (B,H,K,T) f32, fully overwritten each call

    dim3 gA(Tn / 16, Bn);            // (256, 8)
    lwc_weights<<<gA, 256, 0, stream>>>(x, W, wks);

    dim3 gB(Tn / 1024, Hn * 4, Bn);  // (4, 64, 8)
    lwc_apply<<<gB, 256, 0, stream>>>(x, wks, out);
}

// Round 2
// 195.013 us; speedup vs baseline: 2.7337x; 2.7337x over previous
//
#include <hip/hip_runtime.h>
#include <hip/hip_bf16.h>

// Problem constants
constexpr int Bn  = 8;
constexpr int Cn  = 1024;
constexpr int Tn  = 4096;
constexpr int Hn  = 16;
constexpr int Kn  = 15;
constexpr int Fp  = 256;   // padded f dim: row = h*16 + k, k==15 is zero pad

typedef __attribute__((ext_vector_type(8))) short    bf16x8;
typedef __attribute__((ext_vector_type(4))) float    f32x4;

static __device__ __forceinline__ unsigned short f2bf(float f) {
    __hip_bfloat16 h = __float2bfloat16(f);   // round-to-nearest-even
    return *reinterpret_cast<unsigned short*>(&h);
}

// ---------------------------------------------------------------------------
// P1: build padded bf16 W' (256 x 1024) from W (240 x 1024) f32.
// Row m = h*16+k -> W[h*15+k] for k<15, zeros for k==15.
// ---------------------------------------------------------------------------
__global__ __launch_bounds__(256)
void lwc_wpad(const float* __restrict__ W, unsigned short* __restrict__ Wp)
{
    const int idx = (blockIdx.x * 256 + threadIdx.x) * 4;  // over 256*1024
    const int m = idx >> 10, c = idx & 1023;
    const int h = m >> 4, k = m & 15;
    float4 v = make_float4(0.f, 0.f, 0.f, 0.f);
    if (k < 15)
        v = *reinterpret_cast<const float4*>(W + ((size_t)(h * 15 + k)) * Cn + c);
    ushort4 o;
    o.x = f2bf(v.x); o.y = f2bf(v.y); o.z = f2bf(v.z); o.w = f2bf(v.w);
    *reinterpret_cast<ushort4*>(Wp + idx) = o;
}

// ---------------------------------------------------------------------------
// P2: transpose + convert: x (B,C,T) f32 -> xT (B,T,C) bf16.
// 64x64 tiles via LDS (f32, pad 65 to kill bank conflicts).
// grid (T/64, C/64, B), block 256.
// ---------------------------------------------------------------------------
__global__ __launch_bounds__(256)
void lwc_xpose(const float* __restrict__ x, unsigned short* __restrict__ xT)
{
    __shared__ float tile[64 * 65];
    const int tid = threadIdx.x;
    const int t0 = blockIdx.x * 64, c0 = blockIdx.y * 64, b = blockIdx.z;

    // load 64c x 64t, coalesced along t
#pragma unroll
    for (int p = 0; p < 4; ++p) {
        const int cl = p * 16 + (tid >> 4);
        const int tl = (tid & 15) * 4;
        const float4 v = *reinterpret_cast<const float4*>(
            x + ((size_t)b * Cn + c0 + cl) * Tn + t0 + tl);
        float* d = tile + cl * 65 + tl;
        d[0] = v.x; d[1] = v.y; d[2] = v.z; d[3] = v.w;
    }
    __syncthreads();

    // write 64t x 64c, coalesced along c (each thread: 16 c's of one t-row)
    const int trow = tid >> 2;
    const int cb   = (tid & 3) * 16;
    unsigned short obuf[16];
#pragma unroll
    for (int j = 0; j < 16; ++j)
        obuf[j] = f2bf(tile[(cb + j) * 65 + trow]);
    unsigned short* dst = xT + ((size_t)b * Tn + t0 + trow) * Cn + c0 + cb;
    *reinterpret_cast<ulonglong2*>(dst)     = *reinterpret_cast<ulonglong2*>(obuf);
    *reinterpret_cast<ulonglong2*>(dst + 8) = *reinterpret_cast<ulonglong2*>(obuf + 8);
}

// ---------------------------------------------------------------------------
// GEMM + softmax: proj[f][t] = sum_c W'[f][c] * xT[t][c]  (per b),
// then softmax over k (15 rows within each 16-row head fragment),
// write w (B,H,K,T) f32.
// block = 4 waves; wave = 64M x 64N; fragments straight from global
// (W' L2-resident, xT read ~once / L3-resident). grid (T/64, B).
// ---------------------------------------------------------------------------
#define LOADF(dst, P)                                                          \
    {                                                                          \
        _Pragma("unroll") for (int i_ = 0; i_ < 4; ++i_)                       \
            dst[i_] = *reinterpret_cast<const bf16x8*>((P) + i_ * 16 * Cn);    \
    }

#define MFMA16(Af, Bf)                                                         \
    {                                                                          \
        _Pragma("unroll") for (int mi_ = 0; mi_ < 4; ++mi_)                    \
            _Pragma("unroll") for (int ni_ = 0; ni_ < 4; ++ni_)                \
                acc[mi_][ni_] = __builtin_amdgcn_mfma_f32_16x16x32_bf16(       \
                    Af[mi_], Bf[ni_], acc[mi_][ni_], 0, 0, 0);                 \
    }

__global__ __launch_bounds__(256)
void lwc_gemm_softmax(const unsigned short* __restrict__ Wp,
                      const unsigned short* __restrict__ xT,
                      float* __restrict__ wout)
{
    const int tid  = threadIdx.x;
    const int lane = tid & 63;
    const int wv   = tid >> 6;           // wave id 0..3 -> M slab
    const int t0   = blockIdx.x * 64;
    const int b    = blockIdx.y;

    const int lr = lane & 15;            // frag row (A) / col (B)
    const int lg = lane >> 4;            // k-chunk group

    const unsigned short* Ap = Wp + ((size_t)(wv * 64 + lr)) * Cn + lg * 8;
    const unsigned short* Bp = xT + ((size_t)b * Tn + t0 + lr) * Cn + lg * 8;

    f32x4 acc[4][4];
#pragma unroll
    for (int i = 0; i < 4; ++i)
#pragma unroll
        for (int j = 0; j < 4; ++j) acc[i][j] = (f32x4){0.f, 0.f, 0.f, 0.f};

    bf16x8 a0[4], b0[4], a1[4], b1[4];

    // K loop: 32 steps of 32, two-stage frag double buffer
    LOADF(a0, Ap); LOADF(b0, Bp);
    Ap += 32; Bp += 32;
#pragma unroll 1
    for (int ks = 0; ks < 15; ++ks) {
        LOADF(a1, Ap); LOADF(b1, Bp); Ap += 32; Bp += 32;
        MFMA16(a0, b0);
        LOADF(a0, Ap); LOADF(b0, Bp); Ap += 32; Bp += 32;
        MFMA16(a1, b1);
    }
    LOADF(a1, Ap); LOADF(b1, Bp);
    MFMA16(a0, b0);
    MFMA16(a1, b1);

    // ---- softmax over k within each head fragment, write out ----
    const int tcol = lane & 15;
#pragma unroll
    for (int mi = 0; mi < 4; ++mi) {
        const int h = wv * 4 + mi;
        float* hbase = wout + (((size_t)b * Hn + h) * Kn) * Tn + t0;
#pragma unroll
        for (int ni = 0; ni < 4; ++ni) {
            f32x4 v = acc[mi][ni];
            // max over valid taps (k = lg*4 + r, k<15)
            float mx = -3.0e38f;
#pragma unroll
            for (int r = 0; r < 4; ++r)
                if (lg * 4 + r < 15) mx = fmaxf(mx, v[r]);
            mx = fmaxf(mx, __shfl_xor(mx, 16));
            mx = fmaxf(mx, __shfl_xor(mx, 32));
            float e[4], s = 0.f;
#pragma unroll
            for (int r = 0; r < 4; ++r) {
                const int k = lg * 4 + r;
                e[r] = (k < 15) ? __expf(v[r] - mx) : 0.f;
                s += e[r];
            }
            s += __shfl_xor(s, 16);
            s += __shfl_xor(s, 32);
            const float inv = 1.f / s;
#pragma unroll
            for (int r = 0; r < 4; ++r) {
                const int k = lg * 4 + r;
                if (k < 15)
                    hbase[(size_t)k * Tn + ni * 16 + tcol] = e[r] * inv;
            }
        }
    }
}

// ---------------------------------------------------------------------------
// Kernel B: out[b,c,t] = sum_k w[b, c%H, k, t] * x[b, c, t+k-7]   (unchanged)
// ---------------------------------------------------------------------------
__global__ __launch_bounds__(256)
void lwc_apply(const float* __restrict__ x,
               const float* __restrict__ w,
               float* __restrict__ out)
{
    __shared__ __align__(16) float xsh[1040];

    const int tid = threadIdx.x;
    const int t0  = blockIdx.x * 1024;
    const int h   = blockIdx.y >> 2;
    const int rq  = blockIdx.y & 3;
    const int b   = blockIdx.z;
    const int tb  = 4 * tid;

    float4 wreg[15];
#pragma unroll
    for (int k = 0; k < 15; ++k)
        wreg[k] = *reinterpret_cast<const float4*>(
            w + (((size_t)b * Hn + h) * Kn + k) * Tn + t0 + tb);

    for (int rr = 0; rr < 16; ++rr) {
        const int r = rq * 16 + rr;
        const int c = r * Hn + h;
        const float* xrow = x + ((size_t)b * Cn + c) * Tn;

        for (int i = tid; i < 1040; i += 256) {
            const int g = t0 - 8 + i;
            xsh[i] = ((unsigned)g < (unsigned)Tn) ? xrow[g] : 0.f;
        }
        __syncthreads();

        float xv[20];
        const float4* xp = reinterpret_cast<const float4*>(xsh + tb);
#pragma unroll
        for (int q = 0; q < 5; ++q) {
            const float4 a = xp[q];
            xv[4 * q + 0] = a.x; xv[4 * q + 1] = a.y;
            xv[4 * q + 2] = a.z; xv[4 * q + 3] = a.w;
        }

        float ox = 0.f, oy = 0.f, oz = 0.f, ow = 0.f;
#pragma unroll
        for (int k = 0; k < 15; ++k) {
            ox += wreg[k].x * xv[k + 1];
            oy += wreg[k].y * xv[k + 2];
            oz += wreg[k].z * xv[k + 3];
            ow += wreg[k].w * xv[k + 4];
        }
        float4 o; o.x = ox; o.y = oy; o.z = oz; o.w = ow;
        *reinterpret_cast<float4*>(out + ((size_t)b * Cn + c) * Tn + t0 + tb) = o;
        __syncthreads();
    }
}

// ---------------------------------------------------------------------------
// kernel_launch
// d_in[0]=x (B,C,T) f32; d_in[1]=W_lin (240,1024) f32; d_out=(B,C,T) f32.
// Scratch plan:
//   d_ws  : w (B,H,K,T) f32 = 30 MiB (as in round 1)
//   d_out : reused as scratch BEFORE apply overwrites it:
//           [0, 512K)        W' bf16 (256x1024)
//           [1MiB, 65MiB)    xT bf16 (B,T,C)
//           (apply consumes w+x only, then fully overwrites d_out)
// ---------------------------------------------------------------------------
extern "C" void kernel_launch(void* const* d_in, const int* in_sizes, int n_in,
                              void* d_out, int out_size, void* d_ws, size_t ws_size,
                              hipStream_t stream)
{
    const float* x = (const float*)d_in[0];
    const float* W = (const float*)d_in[1];
    float* out     = (float*)d_out;
    float* wks     = (float*)d_ws;

    unsigned short* Wp = (unsigned short*)d_out;                       // 512 KiB
    unsigned short* xT = (unsigned short*)((char*)d_out + (1 << 20));  // 64 MiB

    lwc_wpad<<<dim3(Fp * Cn / 4 / 256), 256, 0, stream>>>(W, Wp);

    dim3 gT(Tn / 64, Cn / 64, Bn);     // (64,16,8)
    lwc_xpose<<<gT, 256, 0, stream>>>(x, xT);

    dim3 gG(Tn / 64, Bn);              // (64,8)
    lwc_gemm_softmax<<<gG, 256, 0, stream>>>(Wp, xT, wks);

    dim3 gB(Tn / 1024, Hn * 4, Bn);    // (4,64,8)
    lwc_apply<<<gB, 256, 0, stream>>>(x, wks, out);
}

// Round 3
// 170.772 us; speedup vs baseline: 3.1217x; 1.1419x over previous
//
#include <hip/hip_runtime.h>
#include <hip/hip_bf16.h>

// Problem constants
constexpr int Bn  = 8;
constexpr int Cn  = 1024;
constexpr int Tn  = 4096;
constexpr int Hn  = 16;
constexpr int Kn  = 15;
constexpr int Fp  = 256;   // padded f dim: row = h*16 + k, k==15 is zero pad

typedef __attribute__((ext_vector_type(8))) short    bf16x8;
typedef __attribute__((ext_vector_type(4))) float    f32x4;

static __device__ __forceinline__ unsigned short f2bf(float f) {
    __hip_bfloat16 h = __float2bfloat16(f);   // round-to-nearest-even
    return *reinterpret_cast<unsigned short*>(&h);
}

// ---------------------------------------------------------------------------
// P1: build padded bf16 W' (256 x 1024) from W (240 x 1024) f32.
// ---------------------------------------------------------------------------
__global__ __launch_bounds__(256)
void lwc_wpad(const float* __restrict__ W, unsigned short* __restrict__ Wp)
{
    const int idx = (blockIdx.x * 256 + threadIdx.x) * 4;  // over 256*1024
    const int m = idx >> 10, c = idx & 1023;
    const int h = m >> 4, k = m & 15;
    float4 v = make_float4(0.f, 0.f, 0.f, 0.f);
    if (k < 15)
        v = *reinterpret_cast<const float4*>(W + ((size_t)(h * 15 + k)) * Cn + c);
    ushort4 o;
    o.x = f2bf(v.x); o.y = f2bf(v.y); o.z = f2bf(v.z); o.w = f2bf(v.w);
    *reinterpret_cast<ushort4*>(Wp + idx) = o;
}

// ---------------------------------------------------------------------------
// P2: transpose + convert: x (B,C,T) f32 -> xT (B,T,C) bf16.
// ---------------------------------------------------------------------------
__global__ __launch_bounds__(256)
void lwc_xpose(const float* __restrict__ x, unsigned short* __restrict__ xT)
{
    __shared__ float tile[64 * 65];
    const int tid = threadIdx.x;
    const int t0 = blockIdx.x * 64, c0 = blockIdx.y * 64, b = blockIdx.z;

#pragma unroll
    for (int p = 0; p < 4; ++p) {
        const int cl = p * 16 + (tid >> 4);
        const int tl = (tid & 15) * 4;
        const float4 v = *reinterpret_cast<const float4*>(
            x + ((size_t)b * Cn + c0 + cl) * Tn + t0 + tl);
        float* d = tile + cl * 65 + tl;
        d[0] = v.x; d[1] = v.y; d[2] = v.z; d[3] = v.w;
    }
    __syncthreads();

    const int trow = tid >> 2;
    const int cb   = (tid & 3) * 16;
    unsigned short obuf[16];
#pragma unroll
    for (int j = 0; j < 16; ++j)
        obuf[j] = f2bf(tile[(cb + j) * 65 + trow]);
    unsigned short* dst = xT + ((size_t)b * Tn + t0 + trow) * Cn + c0 + cb;
    *reinterpret_cast<ulonglong2*>(dst)     = *reinterpret_cast<ulonglong2*>(obuf);
    *reinterpret_cast<ulonglong2*>(dst + 8) = *reinterpret_cast<ulonglong2*>(obuf + 8);
}

// ---------------------------------------------------------------------------
// GEMM + softmax (unchanged this round)
// ---------------------------------------------------------------------------
#define LOADF(dst, P)                                                          \
    {                                                                          \
        _Pragma("unroll") for (int i_ = 0; i_ < 4; ++i_)                       \
            dst[i_] = *reinterpret_cast<const bf16x8*>((P) + i_ * 16 * Cn);    \
    }

#define MFMA16(Af, Bf)                                                         \
    {                                                                          \
        _Pragma("unroll") for (int mi_ = 0; mi_ < 4; ++mi_)                    \
            _Pragma("unroll") for (int ni_ = 0; ni_ < 4; ++ni_)                \
                acc[mi_][ni_] = __builtin_amdgcn_mfma_f32_16x16x32_bf16(       \
                    Af[mi_], Bf[ni_], acc[mi_][ni_], 0, 0, 0);                 \
    }

__global__ __launch_bounds__(256)
void lwc_gemm_softmax(const unsigned short* __restrict__ Wp,
                      const unsigned short* __restrict__ xT,
                      float* __restrict__ wout)
{
    const int tid  = threadIdx.x;
    const int lane = tid & 63;
    const int wv   = tid >> 6;
    const int t0   = blockIdx.x * 64;
    const int b    = blockIdx.y;

    const int lr = lane & 15;
    const int lg = lane >> 4;

    const unsigned short* Ap = Wp + ((size_t)(wv * 64 + lr)) * Cn + lg * 8;
    const unsigned short* Bp = xT + ((size_t)b * Tn + t0 + lr) * Cn + lg * 8;

    f32x4 acc[4][4];
#pragma unroll
    for (int i = 0; i < 4; ++i)
#pragma unroll
        for (int j = 0; j < 4; ++j) acc[i][j] = (f32x4){0.f, 0.f, 0.f, 0.f};

    bf16x8 a0[4], b0[4], a1[4], b1[4];

    LOADF(a0, Ap); LOADF(b0, Bp);
    Ap += 32; Bp += 32;
#pragma unroll 1
    for (int ks = 0; ks < 15; ++ks) {
        LOADF(a1, Ap); LOADF(b1, Bp); Ap += 32; Bp += 32;
        MFMA16(a0, b0);
        LOADF(a0, Ap); LOADF(b0, Bp); Ap += 32; Bp += 32;
        MFMA16(a1, b1);
    }
    LOADF(a1, Ap); LOADF(b1, Bp);
    MFMA16(a0, b0);
    MFMA16(a1, b1);

    const int tcol = lane & 15;
#pragma unroll
    for (int mi = 0; mi < 4; ++mi) {
        const int h = wv * 4 + mi;
        float* hbase = wout + (((size_t)b * Hn + h) * Kn) * Tn + t0;
#pragma unroll
        for (int ni = 0; ni < 4; ++ni) {
            f32x4 v = acc[mi][ni];
            float mx = -3.0e38f;
#pragma unroll
            for (int r = 0; r < 4; ++r)
                if (lg * 4 + r < 15) mx = fmaxf(mx, v[r]);
            mx = fmaxf(mx, __shfl_xor(mx, 16));
            mx = fmaxf(mx, __shfl_xor(mx, 32));
            float e[4], s = 0.f;
#pragma unroll
            for (int r = 0; r < 4; ++r) {
                const int k = lg * 4 + r;
                e[r] = (k < 15) ? __expf(v[r] - mx) : 0.f;
                s += e[r];
            }
            s += __shfl_xor(s, 16);
            s += __shfl_xor(s, 32);
            const float inv = 1.f / s;
#pragma unroll
            for (int r = 0; r < 4; ++r) {
                const int k = lg * 4 + r;
                if (k < 15)
                    hbase[(size_t)k * Tn + ni * 16 + tcol] = e[r] * inv;
            }
        }
    }
}

// ---------------------------------------------------------------------------
// Kernel B (REWRITE): no LDS, no barriers. Direct global loads; L1 absorbs
// the 5x halo overlap between neighboring lanes. Edge threads (sequence
// boundary only) take a scalar predicated path.
// grid (Tn/1024, Hn*4, Bn), block 256; thread covers 4 t's x 16 channels.
// ---------------------------------------------------------------------------
__global__ __launch_bounds__(256)
void lwc_apply(const float* __restrict__ x,
               const float* __restrict__ w,
               float* __restrict__ out)
{
    const int tid = threadIdx.x;
    const int t0  = blockIdx.x * 1024;
    const int h   = blockIdx.y >> 2;
    const int rq  = blockIdx.y & 3;
    const int b   = blockIdx.z;
    const int tb  = 4 * tid;

    // per-thread taps: wreg[k] covers global t = t0+tb .. t0+tb+3
    float4 wreg[15];
#pragma unroll
    for (int k = 0; k < 15; ++k)
        wreg[k] = *reinterpret_cast<const float4*>(
            w + (((size_t)b * Hn + h) * Kn + k) * Tn + t0 + tb);

    const int g0 = t0 + tb - 8;                      // window start (aligned)
    const bool interior = (g0 >= 0) && (g0 + 20 <= Tn);

#pragma unroll 2
    for (int rr = 0; rr < 16; ++rr) {
        const int c = (rq * 16 + rr) * Hn + h;
        const float* xrow = x + ((size_t)b * Cn + c) * Tn;

        float xv[20];
        if (interior) {
            const float4* xp = reinterpret_cast<const float4*>(xrow + g0);
#pragma unroll
            for (int q = 0; q < 5; ++q) {
                const float4 a = xp[q];
                xv[4 * q + 0] = a.x; xv[4 * q + 1] = a.y;
                xv[4 * q + 2] = a.z; xv[4 * q + 3] = a.w;
            }
        } else {
#pragma unroll
            for (int i = 0; i < 20; ++i) {
                const int g = g0 + i;
                xv[i] = ((unsigned)g < (unsigned)Tn) ? xrow[g] : 0.f;
            }
        }

        // out(t = t0+tb+j) = sum_k wreg[k][j] * x[t+k-7] = xv[j+k+1]
        float ox = 0.f, oy = 0.f, oz = 0.f, ow = 0.f;
#pragma unroll
        for (int k = 0; k < 15; ++k) {
            ox += wreg[k].x * xv[k + 1];
            oy += wreg[k].y * xv[k + 2];
            oz += wreg[k].z * xv[k + 3];
            ow += wreg[k].w * xv[k + 4];
        }
        float4 o; o.x = ox; o.y = oy; o.z = oz; o.w = ow;
        *reinterpret_cast<float4*>(out + ((size_t)b * Cn + c) * Tn + t0 + tb) = o;
    }
}

// ---------------------------------------------------------------------------
// kernel_launch — scratch plan unchanged:
//   d_ws  : w (B,H,K,T) f32 = 30 MiB
//   d_out : [0,512K) W' bf16 ; [1MiB,65MiB) xT bf16 (consumed before apply
//           overwrites d_out)
// ---------------------------------------------------------------------------
extern "C" void kernel_launch(void* const* d_in, const int* in_sizes, int n_in,
                              void* d_out, int out_size, void* d_ws, size_t ws_size,
                              hipStream_t stream)
{
    const float* x = (const float*)d_in[0];
    const float* W = (const float*)d_in[1];
    float* out     = (float*)d_out;
    float* wks     = (float*)d_ws;

    unsigned short* Wp = (unsigned short*)d_out;                       // 512 KiB
    unsigned short* xT = (unsigned short*)((char*)d_out + (1 << 20));  // 64 MiB

    lwc_wpad<<<dim3(Fp * Cn / 4 / 256), 256, 0, stream>>>(W, Wp);

    dim3 gT(Tn / 64, Cn / 64, Bn);     // (64,16,8)
    lwc_xpose<<<gT, 256, 0, stream>>>(x, xT);

    dim3 gG(Tn / 64, Bn);              // (64,8)
    lwc_gemm_softmax<<<gG, 256, 0, stream>>>(Wp, xT, wks);

    dim3 gB(Tn / 1024, Hn * 4, Bn);    // (4,64,8)
    lwc_apply<<<gB, 256, 0, stream>>>(x, wks, out);
}

// Round 4
// 120.203 us; speedup vs baseline: 4.4350x; 1.4207x over previous
//
#include <hip/hip_runtime.h>
#include <hip/hip_bf16.h>

// Problem constants
constexpr int Bn  = 8;
constexpr int Cn  = 1024;
constexpr int Tn  = 4096;
constexpr int Hn  = 16;
constexpr int Kn  = 15;
constexpr int Fp  = 256;   // padded f dim: row = h*16 + k, k==15 is zero pad

typedef __attribute__((ext_vector_type(8))) short    bf16x8;
typedef __attribute__((ext_vector_type(4))) float    f32x4;

static __device__ __forceinline__ unsigned short f2bf(float f) {
    __hip_bfloat16 h = __float2bfloat16(f);   // round-to-nearest-even
    return *reinterpret_cast<unsigned short*>(&h);
}

// ---------------------------------------------------------------------------
// P1: build padded bf16 W' (256 x 1024) from W (240 x 1024) f32.
// ---------------------------------------------------------------------------
__global__ __launch_bounds__(256)
void lwc_wpad(const float* __restrict__ W, unsigned short* __restrict__ Wp)
{
    const int idx = (blockIdx.x * 256 + threadIdx.x) * 4;  // over 256*1024
    const int m = idx >> 10, c = idx & 1023;
    const int h = m >> 4, k = m & 15;
    float4 v = make_float4(0.f, 0.f, 0.f, 0.f);
    if (k < 15)
        v = *reinterpret_cast<const float4*>(W + ((size_t)(h * 15 + k)) * Cn + c);
    ushort4 o;
    o.x = f2bf(v.x); o.y = f2bf(v.y); o.z = f2bf(v.z); o.w = f2bf(v.w);
    *reinterpret_cast<ushort4*>(Wp + idx) = o;
}

// ---------------------------------------------------------------------------
// Fused transpose + GEMM + softmax.
// grid (Tn/64, Bn), block 256 (4 waves). Wave wv owns M rows [wv*64, wv*64+64)
// of W' (heads wv*4..wv*4+3); all waves share the 64-t N tile.
//
// K-loop: 8 chunks of 128 c. Staging thread (tcell=tid&15, coct=tid>>4) loads
// x[b, ck*128+coct*8+j, t0+tcell*4+tt] (8 coalesced float4), packs 8 c's at
// fixed t into one 16B LDS row: layout [cg=c/8][slot=t][8c] bf16, swizzled
// slot^=(cg&7) (identical XOR on write and read -> conflict-free both ways).
// B-frag (ks,ni) for lane (lr,lg): LDS[ks*4+lg][ni*16+lr][0..8) = 8 c's at
// fixed t  == exactly what the old global-xT read delivered.
// ---------------------------------------------------------------------------
__global__ __launch_bounds__(256)
void lwc_fused_weights(const float* __restrict__ x,
                       const unsigned short* __restrict__ Wp,
                       float* __restrict__ wout)
{
    // 2 buffers x [16 cg][64 slot][8 c] ushort = 2*8192 ushorts = 32 KiB
    __shared__ __align__(16) unsigned short xs[2 * 16 * 64 * 8];

    const int tid  = threadIdx.x;
    const int lane = tid & 63;
    const int wv   = tid >> 6;
    const int t0   = blockIdx.x * 64;
    const int b    = blockIdx.y;

    const int lr = lane & 15;
    const int lg = lane >> 4;

    // staging mapping
    const int tcell = tid & 15;        // 4 t's: t0 + tcell*4 + tt
    const int coct  = tid >> 4;        // 8 c's: ck*128 + coct*8 + j
    const float* xbase = x + (size_t)b * Cn * Tn + t0 + tcell * 4;

    f32x4 acc[4][4];
#pragma unroll
    for (int i = 0; i < 4; ++i)
#pragma unroll
        for (int j = 0; j < 4; ++j) acc[i][j] = (f32x4){0.f, 0.f, 0.f, 0.f};

    // prologue: load chunk 0
    float4 ld[8];
#pragma unroll
    for (int j = 0; j < 8; ++j)
        ld[j] = *reinterpret_cast<const float4*>(
            xbase + (size_t)(coct * 8 + j) * Tn);

    const unsigned short* Abase = Wp + ((size_t)(wv * 64 + lr)) * Cn + lg * 8;
    const int lrx0 = lr ^ lg;          // read-side swizzle, ks even
    unsigned short* wrow = xs + coct * 512;   // write row base (buf added below)
    const int csw = coct & 7;                 // write-side swizzle

#pragma unroll 1
    for (int ck = 0; ck < 8; ++ck) {
        const int buf = (ck & 1) * 8192;

        // ---- convert + LDS write (uses ld from previous iteration) ----
        float cf[8][4];
#pragma unroll
        for (int j = 0; j < 8; ++j) {
            cf[j][0] = ld[j].x; cf[j][1] = ld[j].y;
            cf[j][2] = ld[j].z; cf[j][3] = ld[j].w;
        }
#pragma unroll
        for (int tt = 0; tt < 4; ++tt) {
            const int slot  = tcell * 4 + tt;
            const int slotw = slot ^ csw;
            bf16x8 pk;
#pragma unroll
            for (int j = 0; j < 8; ++j) pk[j] = (short)f2bf(cf[j][tt]);
            *reinterpret_cast<bf16x8*>(wrow + buf + slotw * 8) = pk;
        }

        __syncthreads();

        // ---- prefetch next chunk (overlaps MFMA below) ----
        if (ck < 7) {
#pragma unroll
            for (int j = 0; j < 8; ++j)
                ld[j] = *reinterpret_cast<const float4*>(
                    xbase + (size_t)((ck + 1) * 128 + coct * 8 + j) * Tn);
        }

        // ---- MFMA over this chunk: 4 K-steps of 32 ----
        const unsigned short* Apc = Abase + ck * 128;
#pragma unroll
        for (int ks = 0; ks < 4; ++ks) {
            bf16x8 af[4], bfr[4];
            const unsigned short* ap = Apc + ks * 32;
#pragma unroll
            for (int mi = 0; mi < 4; ++mi)
                af[mi] = *reinterpret_cast<const bf16x8*>(ap + (size_t)mi * 16 * Cn);
            const int lrx = lrx0 ^ ((ks & 1) << 2);
            const unsigned short* bp = xs + buf + (ks * 4 + lg) * 512 + lrx * 8;
#pragma unroll
            for (int ni = 0; ni < 4; ++ni)
                bfr[ni] = *reinterpret_cast<const bf16x8*>(bp + ni * 128);
#pragma unroll
            for (int mi = 0; mi < 4; ++mi)
#pragma unroll
                for (int ni = 0; ni < 4; ++ni)
                    acc[mi][ni] = __builtin_amdgcn_mfma_f32_16x16x32_bf16(
                        af[mi], bfr[ni], acc[mi][ni], 0, 0, 0);
        }
    }

    // ---- softmax over k within each head fragment, write w (B,H,K,T) ----
    const int tcol = lane & 15;
#pragma unroll
    for (int mi = 0; mi < 4; ++mi) {
        const int h = wv * 4 + mi;
        float* hbase = wout + (((size_t)b * Hn + h) * Kn) * Tn + t0;
#pragma unroll
        for (int ni = 0; ni < 4; ++ni) {
            f32x4 v = acc[mi][ni];
            float mx = -3.0e38f;
#pragma unroll
            for (int r = 0; r < 4; ++r)
                if (lg * 4 + r < 15) mx = fmaxf(mx, v[r]);
            mx = fmaxf(mx, __shfl_xor(mx, 16));
            mx = fmaxf(mx, __shfl_xor(mx, 32));
            float e[4], s = 0.f;
#pragma unroll
            for (int r = 0; r < 4; ++r) {
                const int k = lg * 4 + r;
                e[r] = (k < 15) ? __expf(v[r] - mx) : 0.f;
                s += e[r];
            }
            s += __shfl_xor(s, 16);
            s += __shfl_xor(s, 32);
            const float inv = 1.f / s;
#pragma unroll
            for (int r = 0; r < 4; ++r) {
                const int k = lg * 4 + r;
                if (k < 15)
                    hbase[(size_t)k * Tn + ni * 16 + tcol] = e[r] * inv;
            }
        }
    }
}

// ---------------------------------------------------------------------------
// Kernel B: no LDS, no barriers; L1 absorbs the 5x halo overlap.
// ---------------------------------------------------------------------------
__global__ __launch_bounds__(256)
void lwc_apply(const float* __restrict__ x,
               const float* __restrict__ w,
               float* __restrict__ out)
{
    const int tid = threadIdx.x;
    const int t0  = blockIdx.x * 1024;
    const int h   = blockIdx.y >> 2;
    const int rq  = blockIdx.y & 3;
    const int b   = blockIdx.z;
    const int tb  = 4 * tid;

    float4 wreg[15];
#pragma unroll
    for (int k = 0; k < 15; ++k)
        wreg[k] = *reinterpret_cast<const float4*>(
            w + (((size_t)b * Hn + h) * Kn + k) * Tn + t0 + tb);

    const int g0 = t0 + tb - 8;
    const bool interior = (g0 >= 0) && (g0 + 20 <= Tn);

#pragma unroll 2
    for (int rr = 0; rr < 16; ++rr) {
        const int c = (rq * 16 + rr) * Hn + h;
        const float* xrow = x + ((size_t)b * Cn + c) * Tn;

        float xv[20];
        if (interior) {
            const float4* xp = reinterpret_cast<const float4*>(xrow + g0);
#pragma unroll
            for (int q = 0; q < 5; ++q) {
                const float4 a = xp[q];
                xv[4 * q + 0] = a.x; xv[4 * q + 1] = a.y;
                xv[4 * q + 2] = a.z; xv[4 * q + 3] = a.w;
            }
        } else {
#pragma unroll
            for (int i = 0; i < 20; ++i) {
                const int g = g0 + i;
                xv[i] = ((unsigned)g < (unsigned)Tn) ? xrow[g] : 0.f;
            }
        }

        float ox = 0.f, oy = 0.f, oz = 0.f, ow = 0.f;
#pragma unroll
        for (int k = 0; k < 15; ++k) {
            ox += wreg[k].x * xv[k + 1];
            oy += wreg[k].y * xv[k + 2];
            oz += wreg[k].z * xv[k + 3];
            ow += wreg[k].w * xv[k + 4];
        }
        float4 o; o.x = ox; o.y = oy; o.z = oz; o.w = ow;
        *reinterpret_cast<float4*>(out + ((size_t)b * Cn + c) * Tn + t0 + tb) = o;
    }
}

// ---------------------------------------------------------------------------
// kernel_launch — scratch plan:
//   d_ws  : w (B,H,K,T) f32 = 30 MiB
//   d_out : [0,512K) W' bf16 (consumed by fused_weights before apply
//           overwrites d_out)
// ---------------------------------------------------------------------------
extern "C" void kernel_launch(void* const* d_in, const int* in_sizes, int n_in,
                              void* d_out, int out_size, void* d_ws, size_t ws_size,
                              hipStream_t stream)
{
    const float* x = (const float*)d_in[0];
    const float* W = (const float*)d_in[1];
    float* out     = (float*)d_out;
    float* wks     = (float*)d_ws;

    unsigned short* Wp = (unsigned short*)d_out;   // 512 KiB scratch in d_out

    lwc_wpad<<<dim3(Fp * Cn / 4 / 256), 256, 0, stream>>>(W, Wp);

    dim3 gF(Tn / 64, Bn);              // (64, 8)
    lwc_fused_weights<<<gF, 256, 0, stream>>>(x, Wp, wks);

    dim3 gB(Tn / 1024, Hn * 4, Bn);    // (4, 64, 8)
    lwc_apply<<<gB, 256, 0, stream>>>(x, wks, out);
}